// Round 1
// baseline (3787.251 us; speedup 1.0000x reference)
//
#include <hip/hip_runtime.h>

#define D 128
#define ND 100000
#define NP 50000
#define NE_DD 800000
#define NE_DP 600000
#define NE_PD 600000

typedef __bf16 bf16;
typedef __attribute__((ext_vector_type(8))) __bf16 bf16x8;
typedef __attribute__((ext_vector_type(4))) __bf16 bf16x4;
typedef __attribute__((ext_vector_type(4))) float f32x4;

// ---------------- workspace layout (byte offsets) ----------------
#define OFF_WDD   0UL
#define OFF_WDP   32768UL
#define OFF_WPD   65536UL
#define OFF_WDRUG 98304UL
#define OFF_WPROT 163840UL
#define OFF_YDD   229376UL
#define OFF_YDP   (OFF_YDD + 25600000UL)
#define OFF_YPD   (OFF_YDP + 25600000UL)
#define OFF_SDD   (OFF_YPD + 12800000UL)
#define OFF_SPD   (OFF_SDD + 51200000UL)
#define OFF_SDP   (OFF_SPD + 51200000UL)
#define OFF_CDD   (OFF_SDP + 25600000UL)
#define OFF_CPD   (OFF_CDD + 400000UL)
#define OFF_CDP   (OFF_CPD + 400000UL)
#define WS_TOTAL  (OFF_CDP + 200000UL)
#define ZERO_BYTES (WS_TOTAL - OFF_SDD)   /* 129,000,000 bytes: s_* and c_* */

// ---------------- zero the accumulators (ws is poisoned 0xAA every call) ----
__global__ __launch_bounds__(256) void zero_kernel(float4* __restrict__ p, long n4) {
    long i = (long)blockIdx.x * 256 + threadIdx.x;
    if (i < n4) p[i] = make_float4(0.f, 0.f, 0.f, 0.f);
}

// ---------------- convert the 5 weight matrices to bf16 --------------------
__global__ __launch_bounds__(256) void prep_w_kernel(
    const float* __restrict__ w0, const float* __restrict__ w1,
    const float* __restrict__ w2, const float* __restrict__ w3,
    const float* __restrict__ w4,
    bf16* __restrict__ o0, bf16* __restrict__ o1, bf16* __restrict__ o2,
    bf16* __restrict__ o3, bf16* __restrict__ o4)
{
    int m = blockIdx.y;
    const float* src; bf16* dst; int n;
    switch (m) {
        case 0: src = w0; dst = o0; n = D * D; break;
        case 1: src = w1; dst = o1; n = D * D; break;
        case 2: src = w2; dst = o2; n = D * D; break;
        case 3: src = w3; dst = o3; n = D * 2 * D; break;
        default: src = w4; dst = o4; n = D * 2 * D; break;
    }
    int i = blockIdx.x * 256 + threadIdx.x;
    if (i < n) dst[i] = (bf16)src[i];
}

// ---------------- y1 = relu(x @ W1^T), y2 = relu(x @ W2^T) -----------------
// block = 256 (4 waves), each wave owns a 16-row m-tile; 64 rows per block.
// MFMA 16x16x32 bf16. A-frag: lane holds A[m=lane&15][k=(lane>>4)*8+j].
// B-frag: lane holds B[k][n=lane&15] = W[n][k] (W row-major over k -> uint4 load).
// C/D: col = lane&15, row = (lane>>4)*4 + reg.
__global__ __launch_bounds__(256) void transform2_kernel(
    const float* __restrict__ x, const bf16* __restrict__ W1,
    const bf16* __restrict__ W2, bf16* __restrict__ y1, bf16* __restrict__ y2,
    int M)
{
    int lane = threadIdx.x & 63;
    int wave = threadIdx.x >> 6;
    int q = lane >> 4, c = lane & 15;
    int mb = blockIdx.x * 64 + wave * 16;
    int rowA = min(mb + c, M - 1);

    f32x4 acc1[8], acc2[8];
#pragma unroll
    for (int i = 0; i < 8; i++) { acc1[i] = 0; acc2[i] = 0; }

    const float* xrow = x + (long)rowA * D;
#pragma unroll
    for (int kb = 0; kb < 4; kb++) {
        int k = kb * 32 + q * 8;
        float4 f0 = *(const float4*)(xrow + k);
        float4 f1 = *(const float4*)(xrow + k + 4);
        bf16x8 a;
        a[0] = (bf16)f0.x; a[1] = (bf16)f0.y; a[2] = (bf16)f0.z; a[3] = (bf16)f0.w;
        a[4] = (bf16)f1.x; a[5] = (bf16)f1.y; a[6] = (bf16)f1.z; a[7] = (bf16)f1.w;
#pragma unroll
        for (int nt = 0; nt < 8; nt++) {
            int n = nt * 16 + c;
            bf16x8 b1 = *(const bf16x8*)(W1 + n * D + k);
            acc1[nt] = __builtin_amdgcn_mfma_f32_16x16x32_bf16(a, b1, acc1[nt], 0, 0, 0);
            bf16x8 b2 = *(const bf16x8*)(W2 + n * D + k);
            acc2[nt] = __builtin_amdgcn_mfma_f32_16x16x32_bf16(a, b2, acc2[nt], 0, 0, 0);
        }
    }
#pragma unroll
    for (int r = 0; r < 4; r++) {
        int row = mb + q * 4 + r;
        if (row < M) {
            bf16* p1 = y1 + (long)row * D + c;
            bf16* p2 = y2 + (long)row * D + c;
#pragma unroll
            for (int nt = 0; nt < 8; nt++) {
                p1[nt * 16] = (bf16)fmaxf(acc1[nt][r], 0.f);
                p2[nt * 16] = (bf16)fmaxf(acc2[nt][r], 0.f);
            }
        }
    }
}

__global__ __launch_bounds__(256) void transform1_kernel(
    const float* __restrict__ x, const bf16* __restrict__ W1,
    bf16* __restrict__ y1, int M)
{
    int lane = threadIdx.x & 63;
    int wave = threadIdx.x >> 6;
    int q = lane >> 4, c = lane & 15;
    int mb = blockIdx.x * 64 + wave * 16;
    int rowA = min(mb + c, M - 1);

    f32x4 acc1[8];
#pragma unroll
    for (int i = 0; i < 8; i++) acc1[i] = 0;

    const float* xrow = x + (long)rowA * D;
#pragma unroll
    for (int kb = 0; kb < 4; kb++) {
        int k = kb * 32 + q * 8;
        float4 f0 = *(const float4*)(xrow + k);
        float4 f1 = *(const float4*)(xrow + k + 4);
        bf16x8 a;
        a[0] = (bf16)f0.x; a[1] = (bf16)f0.y; a[2] = (bf16)f0.z; a[3] = (bf16)f0.w;
        a[4] = (bf16)f1.x; a[5] = (bf16)f1.y; a[6] = (bf16)f1.z; a[7] = (bf16)f1.w;
#pragma unroll
        for (int nt = 0; nt < 8; nt++) {
            int n = nt * 16 + c;
            bf16x8 b1 = *(const bf16x8*)(W1 + n * D + k);
            acc1[nt] = __builtin_amdgcn_mfma_f32_16x16x32_bf16(a, b1, acc1[nt], 0, 0, 0);
        }
    }
#pragma unroll
    for (int r = 0; r < 4; r++) {
        int row = mb + q * 4 + r;
        if (row < M) {
            bf16* p1 = y1 + (long)row * D + c;
#pragma unroll
            for (int nt = 0; nt < 8; nt++)
                p1[nt * 16] = (bf16)fmaxf(acc1[nt][r], 0.f);
        }
    }
}

// ---------------- scatter: s[dst] += y[src]; cnt[dst] += 1 -----------------
// 32 lanes per edge, 4 columns per lane (8B bf16 gather, 4 f32 HW atomics).
__global__ __launch_bounds__(256) void scatter_kernel(
    const bf16* __restrict__ y, const int* __restrict__ src,
    const int* __restrict__ dst, float* __restrict__ s, int* __restrict__ cnt,
    int E)
{
    int t = blockIdx.x * 256 + threadIdx.x;
    int e = t >> 5;
    if (e >= E) return;
    int l = t & 31;
    int si = src[e];
    int di = dst[e];
    bf16x4 v = *(const bf16x4*)(y + (long)si * D + l * 4);
    float* sp = s + (long)di * D + l * 4;
    unsafeAtomicAdd(sp + 0, (float)v[0]);
    unsafeAtomicAdd(sp + 1, (float)v[1]);
    unsafeAtomicAdd(sp + 2, (float)v[2]);
    unsafeAtomicAdd(sp + 3, (float)v[3]);
    if (l == 0) atomicAdd(cnt + di, 1);
}

// ---------------- fused node update: GEMM(K=256) + bias + relu + residual + LN
__global__ __launch_bounds__(256) void node_update_kernel(
    const float* __restrict__ x,
    const float* __restrict__ s1, const int* __restrict__ c1,
    const float* __restrict__ s2, const int* __restrict__ c2,
    const bf16* __restrict__ W, const float* __restrict__ b,
    const float* __restrict__ g, const float* __restrict__ be,
    float* __restrict__ out, int M, int nrel)
{
    int lane = threadIdx.x & 63;
    int wave = threadIdx.x >> 6;
    int q = lane >> 4, c = lane & 15;
    int mb = blockIdx.x * 64 + wave * 16;
    int rowA = min(mb + c, M - 1);

    float inv1, inv2;
    if (nrel == 2) {
        inv1 = 0.5f / fmaxf((float)c1[rowA], 1.0f);
        inv2 = 0.5f / fmaxf((float)c2[rowA], 1.0f);
    } else {
        inv1 = 1.0f / fmaxf((float)c1[rowA], 1.0f);
        inv2 = 0.0f;
    }

    f32x4 acc[8];
#pragma unroll
    for (int i = 0; i < 8; i++) acc[i] = 0;

    const float* xrow  = x  + (long)rowA * D;
    const float* s1row = s1 + (long)rowA * D;
    const float* s2row = s2 + (long)rowA * D;

#pragma unroll
    for (int kb = 0; kb < 8; kb++) {
        bf16x8 a;
        if (kb < 4) {
            int k = kb * 32 + q * 8;
            float4 f0 = *(const float4*)(xrow + k);
            float4 f1 = *(const float4*)(xrow + k + 4);
            a[0] = (bf16)f0.x; a[1] = (bf16)f0.y; a[2] = (bf16)f0.z; a[3] = (bf16)f0.w;
            a[4] = (bf16)f1.x; a[5] = (bf16)f1.y; a[6] = (bf16)f1.z; a[7] = (bf16)f1.w;
        } else {
            int k = (kb - 4) * 32 + q * 8;
            float4 f0 = *(const float4*)(s1row + k);
            float4 f1 = *(const float4*)(s1row + k + 4);
            float v0 = f0.x * inv1, v1 = f0.y * inv1, v2 = f0.z * inv1, v3 = f0.w * inv1;
            float v4 = f1.x * inv1, v5 = f1.y * inv1, v6 = f1.z * inv1, v7 = f1.w * inv1;
            if (nrel == 2) {
                float4 h0 = *(const float4*)(s2row + k);
                float4 h1 = *(const float4*)(s2row + k + 4);
                v0 += h0.x * inv2; v1 += h0.y * inv2; v2 += h0.z * inv2; v3 += h0.w * inv2;
                v4 += h1.x * inv2; v5 += h1.y * inv2; v6 += h1.z * inv2; v7 += h1.w * inv2;
            }
            a[0] = (bf16)v0; a[1] = (bf16)v1; a[2] = (bf16)v2; a[3] = (bf16)v3;
            a[4] = (bf16)v4; a[5] = (bf16)v5; a[6] = (bf16)v6; a[7] = (bf16)v7;
        }
#pragma unroll
        for (int nt = 0; nt < 8; nt++) {
            int n = nt * 16 + c;
            bf16x8 bw = *(const bf16x8*)(W + n * (2 * D) + kb * 32 + q * 8);
            acc[nt] = __builtin_amdgcn_mfma_f32_16x16x32_bf16(a, bw, acc[nt], 0, 0, 0);
        }
    }

    // epilogue: bias + relu + residual + layernorm (rows live in quads)
    float bv[8], gv[8], bev[8];
#pragma unroll
    for (int nt = 0; nt < 8; nt++) {
        int col = nt * 16 + c;
        bv[nt] = b[col]; gv[nt] = g[col]; bev[nt] = be[col];
    }
#pragma unroll
    for (int r = 0; r < 4; r++) {
        int row = mb + q * 4 + r;
        int rowc = min(row, M - 1);
        const float* xr = x + (long)rowc * D + c;
        float v[8];
        float sum = 0.f, sq = 0.f;
#pragma unroll
        for (int nt = 0; nt < 8; nt++) {
            float h = fmaxf(acc[nt][r] + bv[nt], 0.f);
            float t = h + xr[nt * 16];
            v[nt] = t; sum += t; sq += t * t;
        }
#pragma unroll
        for (int m = 1; m < 16; m <<= 1) {
            sum += __shfl_xor(sum, m, 64);
            sq  += __shfl_xor(sq,  m, 64);
        }
        float mu   = sum * (1.f / 128.f);
        float var  = sq  * (1.f / 128.f) - mu * mu;
        float rstd = rsqrtf(var + 1e-5f);
        if (row < M) {
            float* op = out + (long)row * D + c;
#pragma unroll
            for (int nt = 0; nt < 8; nt++)
                op[nt * 16] = (v[nt] - mu) * rstd * gv[nt] + bev[nt];
        }
    }
}

extern "C" void kernel_launch(void* const* d_in, const int* in_sizes, int n_in,
                              void* d_out, int out_size, void* d_ws, size_t ws_size,
                              hipStream_t stream)
{
    const float* x_drug  = (const float*)d_in[0];
    const float* x_prot  = (const float*)d_in[1];
    const float* Wagg_dd = (const float*)d_in[2];
    const float* Wagg_dp = (const float*)d_in[3];
    const float* Wagg_pd = (const float*)d_in[4];
    const float* W_drug  = (const float*)d_in[5];
    const float* b_drug  = (const float*)d_in[6];
    const float* W_prot  = (const float*)d_in[7];
    const float* b_prot  = (const float*)d_in[8];
    const float* g_drug  = (const float*)d_in[9];
    const float* be_drug = (const float*)d_in[10];
    const float* g_prot  = (const float*)d_in[11];
    const float* be_prot = (const float*)d_in[12];
    const int* dd_src = (const int*)d_in[13];
    const int* dd_dst = (const int*)d_in[14];
    const int* dp_src = (const int*)d_in[15];
    const int* dp_dst = (const int*)d_in[16];
    const int* pd_src = (const int*)d_in[17];
    const int* pd_dst = (const int*)d_in[18];

    char* ws = (char*)d_ws;
    bf16* Wdd   = (bf16*)(ws + OFF_WDD);
    bf16* Wdp   = (bf16*)(ws + OFF_WDP);
    bf16* Wpd   = (bf16*)(ws + OFF_WPD);
    bf16* Wdrug = (bf16*)(ws + OFF_WDRUG);
    bf16* Wprot = (bf16*)(ws + OFF_WPROT);
    bf16* y_dd  = (bf16*)(ws + OFF_YDD);
    bf16* y_dp  = (bf16*)(ws + OFF_YDP);
    bf16* y_pd  = (bf16*)(ws + OFF_YPD);
    float* s_dd = (float*)(ws + OFF_SDD);
    float* s_pd = (float*)(ws + OFF_SPD);
    float* s_dp = (float*)(ws + OFF_SDP);
    int* c_dd   = (int*)(ws + OFF_CDD);
    int* c_pd   = (int*)(ws + OFF_CPD);
    int* c_dp   = (int*)(ws + OFF_CDP);
    float* out  = (float*)d_out;

    // 1) zero the scatter accumulators (129 MB)
    long n4 = ZERO_BYTES / 16;
    zero_kernel<<<(int)((n4 + 255) / 256), 256, 0, stream>>>((float4*)(ws + OFF_SDD), n4);

    // 2) weights -> bf16
    prep_w_kernel<<<dim3(128, 5), 256, 0, stream>>>(
        Wagg_dd, Wagg_dp, Wagg_pd, W_drug, W_prot, Wdd, Wdp, Wpd, Wdrug, Wprot);

    // 3) per-node transforms
    transform2_kernel<<<(ND + 63) / 64, 256, 0, stream>>>(x_drug, Wdd, Wdp, y_dd, y_dp, ND);
    transform1_kernel<<<(NP + 63) / 64, 256, 0, stream>>>(x_prot, Wpd, y_pd, NP);

    // 4) edge scatter-adds
    scatter_kernel<<<(NE_DD * 32 + 255) / 256, 256, 0, stream>>>(y_dd, dd_src, dd_dst, s_dd, c_dd, NE_DD);
    scatter_kernel<<<(NE_PD * 32 + 255) / 256, 256, 0, stream>>>(y_pd, pd_src, pd_dst, s_pd, c_pd, NE_PD);
    scatter_kernel<<<(NE_DP * 32 + 255) / 256, 256, 0, stream>>>(y_dp, dp_src, dp_dst, s_dp, c_dp, NE_DP);

    // 5) fused node updates (drug rows 0..ND-1, prot rows ND..ND+NP-1 of out)
    node_update_kernel<<<(ND + 63) / 64, 256, 0, stream>>>(
        x_drug, s_dd, c_dd, s_pd, c_pd, Wdrug, b_drug, g_drug, be_drug, out, ND, 2);
    node_update_kernel<<<(NP + 63) / 64, 256, 0, stream>>>(
        x_prot, s_dp, c_dp, s_dp, c_dp, Wprot, b_prot, g_prot, be_prot,
        out + (long)ND * D, NP, 1);
}

// Round 2
// 730.906 us; speedup vs baseline: 5.1816x; 5.1816x over previous
//
#include <hip/hip_runtime.h>

#define D 128
#define ND 100000
#define NP 50000
#define NE_DD 800000
#define NE_DP 600000
#define NE_PD 600000

#define NTOT 250000      /* concatenated dst counters: [dd:100k][pd:100k][dp:50k] */
#define NC   250880      /* padded to 245*1024 */
#define NB   245         /* scan blocks (1024 elems each) */

typedef __bf16 bf16;
typedef __attribute__((ext_vector_type(8))) __bf16 bf16x8;
typedef __attribute__((ext_vector_type(2))) __bf16 bf16x2;
typedef __attribute__((ext_vector_type(4))) float f32x4;

// ---------------- workspace layout (byte offsets, all 256-aligned) ---------
#define OFF_WDD   0UL
#define OFF_WDP   32768UL
#define OFF_WPD   65536UL
#define OFF_WDRUG 98304UL
#define OFF_WPROT 163840UL
#define OFF_YDD   229376UL                      /* 100k x 128 bf16 = 25.6MB */
#define OFF_YDP   (OFF_YDD + 25600000UL)        /* 100k x 128 bf16 */
#define OFF_YPD   (OFF_YDP + 25600000UL)        /* 50k x 128 bf16 = 12.8MB */
#define OFF_AGGD  (OFF_YPD + 12800000UL)        /* 100k x 128 bf16 */
#define OFF_AGGP  (OFF_AGGD + 25600000UL)       /* 50k x 128 bf16 */
#define OFF_C     (OFF_AGGP + 12800000UL)       /* NC ints */
#define OFF_LOCAL (OFF_C + 1003520UL)           /* NC ints */
#define OFF_BSUM  (OFF_LOCAL + 1003520UL)       /* 256 ints */
#define OFF_RP    (OFF_BSUM + 1024UL)           /* NC ints (row ptrs) */
#define OFF_CUR   (OFF_RP + 1003520UL)          /* NC ints (cursors) */
#define OFF_POOL  (OFF_CUR + 1003520UL)         /* 2M ints (src ids, dst-grouped) */

// ---------------- zero (ws is re-poisoned 0xAA before every timed call) ----
__global__ __launch_bounds__(256) void zero_kernel(float4* __restrict__ p, long n4) {
    long i = (long)blockIdx.x * 256 + threadIdx.x;
    if (i < n4) p[i] = make_float4(0.f, 0.f, 0.f, 0.f);
}

// ---------------- weights -> bf16 ------------------------------------------
__global__ __launch_bounds__(256) void prep_w_kernel(
    const float* __restrict__ w0, const float* __restrict__ w1,
    const float* __restrict__ w2, const float* __restrict__ w3,
    const float* __restrict__ w4,
    bf16* __restrict__ o0, bf16* __restrict__ o1, bf16* __restrict__ o2,
    bf16* __restrict__ o3, bf16* __restrict__ o4)
{
    int m = blockIdx.y;
    const float* src; bf16* dst; int n;
    switch (m) {
        case 0: src = w0; dst = o0; n = D * D; break;
        case 1: src = w1; dst = o1; n = D * D; break;
        case 2: src = w2; dst = o2; n = D * D; break;
        case 3: src = w3; dst = o3; n = D * 2 * D; break;
        default: src = w4; dst = o4; n = D * 2 * D; break;
    }
    int i = blockIdx.x * 256 + threadIdx.x;
    if (i < n) dst[i] = (bf16)src[i];
}

// ---------------- per-node transforms: y = relu(x @ W^T) -------------------
__global__ __launch_bounds__(256) void transform2_kernel(
    const float* __restrict__ x, const bf16* __restrict__ W1,
    const bf16* __restrict__ W2, bf16* __restrict__ y1, bf16* __restrict__ y2,
    int M)
{
    int lane = threadIdx.x & 63;
    int wave = threadIdx.x >> 6;
    int q = lane >> 4, c = lane & 15;
    int mb = blockIdx.x * 64 + wave * 16;
    int rowA = min(mb + c, M - 1);

    f32x4 acc1[8], acc2[8];
#pragma unroll
    for (int i = 0; i < 8; i++) { acc1[i] = 0; acc2[i] = 0; }

    const float* xrow = x + (long)rowA * D;
#pragma unroll
    for (int kb = 0; kb < 4; kb++) {
        int k = kb * 32 + q * 8;
        float4 f0 = *(const float4*)(xrow + k);
        float4 f1 = *(const float4*)(xrow + k + 4);
        bf16x8 a;
        a[0] = (bf16)f0.x; a[1] = (bf16)f0.y; a[2] = (bf16)f0.z; a[3] = (bf16)f0.w;
        a[4] = (bf16)f1.x; a[5] = (bf16)f1.y; a[6] = (bf16)f1.z; a[7] = (bf16)f1.w;
#pragma unroll
        for (int nt = 0; nt < 8; nt++) {
            int n = nt * 16 + c;
            bf16x8 b1 = *(const bf16x8*)(W1 + n * D + k);
            acc1[nt] = __builtin_amdgcn_mfma_f32_16x16x32_bf16(a, b1, acc1[nt], 0, 0, 0);
            bf16x8 b2 = *(const bf16x8*)(W2 + n * D + k);
            acc2[nt] = __builtin_amdgcn_mfma_f32_16x16x32_bf16(a, b2, acc2[nt], 0, 0, 0);
        }
    }
#pragma unroll
    for (int r = 0; r < 4; r++) {
        int row = mb + q * 4 + r;
        if (row < M) {
            bf16* p1 = y1 + (long)row * D + c;
            bf16* p2 = y2 + (long)row * D + c;
#pragma unroll
            for (int nt = 0; nt < 8; nt++) {
                p1[nt * 16] = (bf16)fmaxf(acc1[nt][r], 0.f);
                p2[nt * 16] = (bf16)fmaxf(acc2[nt][r], 0.f);
            }
        }
    }
}

__global__ __launch_bounds__(256) void transform1_kernel(
    const float* __restrict__ x, const bf16* __restrict__ W1,
    bf16* __restrict__ y1, int M)
{
    int lane = threadIdx.x & 63;
    int wave = threadIdx.x >> 6;
    int q = lane >> 4, c = lane & 15;
    int mb = blockIdx.x * 64 + wave * 16;
    int rowA = min(mb + c, M - 1);

    f32x4 acc1[8];
#pragma unroll
    for (int i = 0; i < 8; i++) acc1[i] = 0;

    const float* xrow = x + (long)rowA * D;
#pragma unroll
    for (int kb = 0; kb < 4; kb++) {
        int k = kb * 32 + q * 8;
        float4 f0 = *(const float4*)(xrow + k);
        float4 f1 = *(const float4*)(xrow + k + 4);
        bf16x8 a;
        a[0] = (bf16)f0.x; a[1] = (bf16)f0.y; a[2] = (bf16)f0.z; a[3] = (bf16)f0.w;
        a[4] = (bf16)f1.x; a[5] = (bf16)f1.y; a[6] = (bf16)f1.z; a[7] = (bf16)f1.w;
#pragma unroll
        for (int nt = 0; nt < 8; nt++) {
            int n = nt * 16 + c;
            bf16x8 b1 = *(const bf16x8*)(W1 + n * D + k);
            acc1[nt] = __builtin_amdgcn_mfma_f32_16x16x32_bf16(a, b1, acc1[nt], 0, 0, 0);
        }
    }
#pragma unroll
    for (int r = 0; r < 4; r++) {
        int row = mb + q * 4 + r;
        if (row < M) {
            bf16* p1 = y1 + (long)row * D + c;
#pragma unroll
            for (int nt = 0; nt < 8; nt++)
                p1[nt * 16] = (bf16)fmaxf(acc1[nt][r], 0.f);
        }
    }
}

// ---------------- CSR build: histogram -> exclusive scan -> cursor fill ----
__global__ __launch_bounds__(256) void hist_kernel(
    const int* __restrict__ dst, int E, int base, int* __restrict__ C)
{
    int e = blockIdx.x * 256 + threadIdx.x;
    if (e < E) atomicAdd(C + base + dst[e], 1);
}

__global__ __launch_bounds__(256) void scan1_kernel(
    const int* __restrict__ C, int* __restrict__ local, int* __restrict__ bsum)
{
    __shared__ int ts[256];
    int tid = threadIdx.x;
    int base = blockIdx.x * 1024 + tid * 4;
    int4 v = *(const int4*)(C + base);
    int s = v.x + v.y + v.z + v.w;
    ts[tid] = s;
    __syncthreads();
#pragma unroll
    for (int off = 1; off < 256; off <<= 1) {
        int add = (tid >= off) ? ts[tid - off] : 0;
        __syncthreads();
        ts[tid] += add;
        __syncthreads();
    }
    int excl = ts[tid] - s;
    if (tid == 255) bsum[blockIdx.x] = ts[255];
    int4 w;
    w.x = excl;
    w.y = excl + v.x;
    w.z = w.y + v.y;
    w.w = w.z + v.z;
    *(int4*)(local + base) = w;
}

__global__ __launch_bounds__(256) void scan2_kernel(int* __restrict__ bsum)
{
    __shared__ int ts[256];
    int tid = threadIdx.x;
    int v = (tid < NB) ? bsum[tid] : 0;
    ts[tid] = v;
    __syncthreads();
#pragma unroll
    for (int off = 1; off < 256; off <<= 1) {
        int add = (tid >= off) ? ts[tid - off] : 0;
        __syncthreads();
        ts[tid] += add;
        __syncthreads();
    }
    if (tid < NB) bsum[tid] = ts[tid] - v;
}

__global__ __launch_bounds__(256) void scan3_kernel(
    const int* __restrict__ local, const int* __restrict__ bsum,
    int* __restrict__ rp, int* __restrict__ cur)
{
    int base = blockIdx.x * 1024 + threadIdx.x * 4;
    int off = bsum[blockIdx.x];
    int4 v = *(const int4*)(local + base);
    v.x += off; v.y += off; v.z += off; v.w += off;
    *(int4*)(rp + base) = v;
    *(int4*)(cur + base) = v;
}

__global__ __launch_bounds__(256) void fill_kernel(
    const int* __restrict__ src, const int* __restrict__ dst, int E, int base,
    int* __restrict__ cur, int* __restrict__ pool)
{
    int e = blockIdx.x * 256 + threadIdx.x;
    if (e < E) {
        int pos = atomicAdd(cur + base + dst[e], 1);
        pool[pos] = src[e];
    }
}

// ---------------- gather: per-dst mean(s) over sorted edge lists -----------
// one wave per destination node; lane l owns columns 2l, 2l+1.
__global__ __launch_bounds__(256) void gather_kernel(
    const int* __restrict__ rp, const int* __restrict__ pool,
    const bf16* __restrict__ y_dd, const bf16* __restrict__ y_pd,
    const bf16* __restrict__ y_dp,
    bf16* __restrict__ agg_d, bf16* __restrict__ agg_p)
{
    int wid = blockIdx.x * 4 + (threadIdx.x >> 6);
    int lane = threadIdx.x & 63;
    if (wid < ND) {
        int g = wid;
        int s1 = rp[g],      e1 = rp[g + 1];
        int s2 = rp[ND + g], e2 = rp[ND + g + 1];
        float a0 = 0.f, a1 = 0.f, b0 = 0.f, b1 = 0.f;
        for (int j = s1; j < e1; j++) {
            int sid = pool[j];
            bf16x2 v = *(const bf16x2*)(y_dd + (long)sid * D + lane * 2);
            a0 += (float)v[0]; a1 += (float)v[1];
        }
        for (int j = s2; j < e2; j++) {
            int sid = pool[j];
            bf16x2 v = *(const bf16x2*)(y_pd + (long)sid * D + lane * 2);
            b0 += (float)v[0]; b1 += (float)v[1];
        }
        float i1 = 0.5f / (float)max(e1 - s1, 1);
        float i2 = 0.5f / (float)max(e2 - s2, 1);
        bf16x2 o;
        o[0] = (bf16)(a0 * i1 + b0 * i2);
        o[1] = (bf16)(a1 * i1 + b1 * i2);
        *(bf16x2*)(agg_d + (long)g * D + lane * 2) = o;
    } else if (wid < ND + NP) {
        int p = wid - ND;
        int s1 = rp[2 * ND + p], e1 = rp[2 * ND + p + 1];
        float a0 = 0.f, a1 = 0.f;
        for (int j = s1; j < e1; j++) {
            int sid = pool[j];
            bf16x2 v = *(const bf16x2*)(y_dp + (long)sid * D + lane * 2);
            a0 += (float)v[0]; a1 += (float)v[1];
        }
        float i1 = 1.0f / (float)max(e1 - s1, 1);
        bf16x2 o;
        o[0] = (bf16)(a0 * i1);
        o[1] = (bf16)(a1 * i1);
        *(bf16x2*)(agg_p + (long)p * D + lane * 2) = o;
    }
}

// ---------------- fused node update: GEMM(K=256) + bias+relu+residual+LN ---
__global__ __launch_bounds__(256) void node_update_kernel(
    const float* __restrict__ x, const bf16* __restrict__ agg,
    const bf16* __restrict__ W, const float* __restrict__ b,
    const float* __restrict__ g, const float* __restrict__ be,
    float* __restrict__ out, int M)
{
    int lane = threadIdx.x & 63;
    int wave = threadIdx.x >> 6;
    int q = lane >> 4, c = lane & 15;
    int mb = blockIdx.x * 64 + wave * 16;
    int rowA = min(mb + c, M - 1);

    f32x4 acc[8];
#pragma unroll
    for (int i = 0; i < 8; i++) acc[i] = 0;

    const float* xrow = x + (long)rowA * D;
    const bf16* arow  = agg + (long)rowA * D;

#pragma unroll
    for (int kb = 0; kb < 8; kb++) {
        bf16x8 a;
        if (kb < 4) {
            int k = kb * 32 + q * 8;
            float4 f0 = *(const float4*)(xrow + k);
            float4 f1 = *(const float4*)(xrow + k + 4);
            a[0] = (bf16)f0.x; a[1] = (bf16)f0.y; a[2] = (bf16)f0.z; a[3] = (bf16)f0.w;
            a[4] = (bf16)f1.x; a[5] = (bf16)f1.y; a[6] = (bf16)f1.z; a[7] = (bf16)f1.w;
        } else {
            a = *(const bf16x8*)(arow + (kb - 4) * 32 + q * 8);
        }
#pragma unroll
        for (int nt = 0; nt < 8; nt++) {
            int n = nt * 16 + c;
            bf16x8 bw = *(const bf16x8*)(W + n * (2 * D) + kb * 32 + q * 8);
            acc[nt] = __builtin_amdgcn_mfma_f32_16x16x32_bf16(a, bw, acc[nt], 0, 0, 0);
        }
    }

    float bv[8], gv[8], bev[8];
#pragma unroll
    for (int nt = 0; nt < 8; nt++) {
        int col = nt * 16 + c;
        bv[nt] = b[col]; gv[nt] = g[col]; bev[nt] = be[col];
    }
#pragma unroll
    for (int r = 0; r < 4; r++) {
        int row = mb + q * 4 + r;
        int rowc = min(row, M - 1);
        const float* xr = x + (long)rowc * D + c;
        float v[8];
        float sum = 0.f, sq = 0.f;
#pragma unroll
        for (int nt = 0; nt < 8; nt++) {
            float h = fmaxf(acc[nt][r] + bv[nt], 0.f);
            float t = h + xr[nt * 16];
            v[nt] = t; sum += t; sq += t * t;
        }
#pragma unroll
        for (int m = 1; m < 16; m <<= 1) {
            sum += __shfl_xor(sum, m, 64);
            sq  += __shfl_xor(sq,  m, 64);
        }
        float mu   = sum * (1.f / 128.f);
        float var  = sq  * (1.f / 128.f) - mu * mu;
        float rstd = rsqrtf(var + 1e-5f);
        if (row < M) {
            float* op = out + (long)row * D + c;
#pragma unroll
            for (int nt = 0; nt < 8; nt++)
                op[nt * 16] = (v[nt] - mu) * rstd * gv[nt] + bev[nt];
        }
    }
}

extern "C" void kernel_launch(void* const* d_in, const int* in_sizes, int n_in,
                              void* d_out, int out_size, void* d_ws, size_t ws_size,
                              hipStream_t stream)
{
    const float* x_drug  = (const float*)d_in[0];
    const float* x_prot  = (const float*)d_in[1];
    const float* Wagg_dd = (const float*)d_in[2];
    const float* Wagg_dp = (const float*)d_in[3];
    const float* Wagg_pd = (const float*)d_in[4];
    const float* W_drug  = (const float*)d_in[5];
    const float* b_drug  = (const float*)d_in[6];
    const float* W_prot  = (const float*)d_in[7];
    const float* b_prot  = (const float*)d_in[8];
    const float* g_drug  = (const float*)d_in[9];
    const float* be_drug = (const float*)d_in[10];
    const float* g_prot  = (const float*)d_in[11];
    const float* be_prot = (const float*)d_in[12];
    const int* dd_src = (const int*)d_in[13];
    const int* dd_dst = (const int*)d_in[14];
    const int* dp_src = (const int*)d_in[15];
    const int* dp_dst = (const int*)d_in[16];
    const int* pd_src = (const int*)d_in[17];
    const int* pd_dst = (const int*)d_in[18];

    char* ws = (char*)d_ws;
    bf16* Wdd   = (bf16*)(ws + OFF_WDD);
    bf16* Wdp   = (bf16*)(ws + OFF_WDP);
    bf16* Wpd   = (bf16*)(ws + OFF_WPD);
    bf16* Wdrug = (bf16*)(ws + OFF_WDRUG);
    bf16* Wprot = (bf16*)(ws + OFF_WPROT);
    bf16* y_dd  = (bf16*)(ws + OFF_YDD);
    bf16* y_dp  = (bf16*)(ws + OFF_YDP);
    bf16* y_pd  = (bf16*)(ws + OFF_YPD);
    bf16* agg_d = (bf16*)(ws + OFF_AGGD);
    bf16* agg_p = (bf16*)(ws + OFF_AGGP);
    int* C      = (int*)(ws + OFF_C);
    int* local  = (int*)(ws + OFF_LOCAL);
    int* bsum   = (int*)(ws + OFF_BSUM);
    int* rp     = (int*)(ws + OFF_RP);
    int* cur    = (int*)(ws + OFF_CUR);
    int* pool   = (int*)(ws + OFF_POOL);
    float* out  = (float*)d_out;

    // 1) zero the padded histogram counters (~1 MB)
    zero_kernel<<<NB, 256, 0, stream>>>((float4*)C, (long)NC / 4);

    // 2) weights -> bf16
    prep_w_kernel<<<dim3(128, 5), 256, 0, stream>>>(
        Wagg_dd, Wagg_dp, Wagg_pd, W_drug, W_prot, Wdd, Wdp, Wpd, Wdrug, Wprot);

    // 3) per-node transforms
    transform2_kernel<<<(ND + 63) / 64, 256, 0, stream>>>(x_drug, Wdd, Wdp, y_dd, y_dp, ND);
    transform1_kernel<<<(NP + 63) / 64, 256, 0, stream>>>(x_prot, Wpd, y_pd, NP);

    // 4) CSR build: histogram -> scan -> fill (dst-grouped source ids)
    hist_kernel<<<(NE_DD + 255) / 256, 256, 0, stream>>>(dd_dst, NE_DD, 0, C);
    hist_kernel<<<(NE_PD + 255) / 256, 256, 0, stream>>>(pd_dst, NE_PD, ND, C);
    hist_kernel<<<(NE_DP + 255) / 256, 256, 0, stream>>>(dp_dst, NE_DP, 2 * ND, C);
    scan1_kernel<<<NB, 256, 0, stream>>>(C, local, bsum);
    scan2_kernel<<<1, 256, 0, stream>>>(bsum);
    scan3_kernel<<<NB, 256, 0, stream>>>(local, bsum, rp, cur);
    fill_kernel<<<(NE_DD + 255) / 256, 256, 0, stream>>>(dd_src, dd_dst, NE_DD, 0, cur, pool);
    fill_kernel<<<(NE_PD + 255) / 256, 256, 0, stream>>>(pd_src, pd_dst, NE_PD, ND, cur, pool);
    fill_kernel<<<(NE_DP + 255) / 256, 256, 0, stream>>>(dp_src, dp_dst, NE_DP, 2 * ND, cur, pool);

    // 5) gather + mean (0.5 two-relation combine fused), write bf16 agg
    gather_kernel<<<(ND + NP + 3) / 4, 256, 0, stream>>>(
        rp, pool, y_dd, y_pd, y_dp, agg_d, agg_p);

    // 6) fused node updates
    node_update_kernel<<<(ND + 63) / 64, 256, 0, stream>>>(
        x_drug, agg_d, Wdrug, b_drug, g_drug, be_drug, out, ND);
    node_update_kernel<<<(NP + 63) / 64, 256, 0, stream>>>(
        x_prot, agg_p, Wprot, b_prot, g_prot, be_prot, out + (long)ND * D, NP);
}

// Round 3
// 591.772 us; speedup vs baseline: 6.3999x; 1.2351x over previous
//
#include <hip/hip_runtime.h>

#define D 128
#define ND 100000
#define NP 50000
#define NE_DD 800000
#define NE_DP 600000
#define NE_PD 600000
#define NE_TOT 2000000

#define NTOT 250000      /* concatenated dst counters: [dd:100k][pd:100k][dp:50k] */
#define NC   250880      /* padded to 245*1024 */
#define NB   245         /* scan blocks (1024 elems each) */

#define NBLK_D 1563      /* (ND+63)/64 */
#define NBLK_P 782       /* (NP+63)/64 */

typedef __bf16 bf16;
typedef __attribute__((ext_vector_type(8))) __bf16 bf16x8;
typedef __attribute__((ext_vector_type(4))) float f32x4;

// ---------------- workspace layout (byte offsets, 16B-aligned) -------------
#define OFF_WDD   0UL
#define OFF_WDP   32768UL
#define OFF_WPD   65536UL
#define OFF_WDRUG 98304UL
#define OFF_WPROT 163840UL
#define OFF_YDD   229376UL                      /* 100k x 128 bf16 */
#define OFF_YDP   (OFF_YDD + 25600000UL)        /* 100k x 128 bf16 */
#define OFF_YPD   (OFF_YDP + 25600000UL)        /* 50k x 128 bf16 */
#define OFF_AGGD  (OFF_YPD + 12800000UL)        /* 100k x 128 bf16 */
#define OFF_AGGP  (OFF_AGGD + 25600000UL)       /* 50k x 128 bf16 */
#define OFF_C     (OFF_AGGP + 12800000UL)       /* NC ints (histogram) */
#define OFF_CUR2  (OFF_C + 1003520UL)           /* NTOT ints (fill cursors) */
#define OFF_LOCAL (OFF_CUR2 + 1000000UL)        /* NC ints (block-local scan) */
#define OFF_BSUM  (OFF_LOCAL + 1003520UL)       /* 256 ints (block sums) */
#define OFF_POOL  (OFF_BSUM + 1024UL)           /* 2M ints (dst-grouped src ids) */
#define ZERO_B    2003520UL                     /* C + cur2, contiguous */
#define NZ4       125220                        /* ZERO_B / 16 */

// ---------------- prep: weights->bf16  +  zero C/cur2 ----------------------
__global__ __launch_bounds__(256) void prep_kernel(
    const float* __restrict__ w0, const float* __restrict__ w1,
    const float* __restrict__ w2, const float* __restrict__ w3,
    const float* __restrict__ w4,
    bf16* __restrict__ o0, bf16* __restrict__ o1, bf16* __restrict__ o2,
    bf16* __restrict__ o3, bf16* __restrict__ o4,
    float4* __restrict__ zbase)
{
    int m = blockIdx.y;
    int i = blockIdx.x * 256 + threadIdx.x;
    if (m == 5) {
        if (i < NZ4) zbase[i] = make_float4(0.f, 0.f, 0.f, 0.f);
        return;
    }
    const float* src; bf16* dst; int n;
    switch (m) {
        case 0: src = w0; dst = o0; n = D * D; break;
        case 1: src = w1; dst = o1; n = D * D; break;
        case 2: src = w2; dst = o2; n = D * D; break;
        case 3: src = w3; dst = o3; n = D * 2 * D; break;
        default: src = w4; dst = o4; n = D * 2 * D; break;
    }
    if (i < n) dst[i] = (bf16)src[i];
}

// ---------------- per-node transforms: y = relu(x @ W^T), both types -------
__device__ __forceinline__ void transform_body(
    const float* __restrict__ x, const bf16* __restrict__ W1,
    const bf16* __restrict__ W2, bf16* __restrict__ y1, bf16* __restrict__ y2,
    int M, int blk, bool two)
{
    int lane = threadIdx.x & 63;
    int wave = threadIdx.x >> 6;
    int q = lane >> 4, c = lane & 15;
    int mb = blk * 64 + wave * 16;
    int rowA = min(mb + c, M - 1);

    f32x4 acc1[8], acc2[8];
#pragma unroll
    for (int i = 0; i < 8; i++) { acc1[i] = 0; acc2[i] = 0; }

    const float* xrow = x + (long)rowA * D;
#pragma unroll
    for (int kb = 0; kb < 4; kb++) {
        int k = kb * 32 + q * 8;
        float4 f0 = *(const float4*)(xrow + k);
        float4 f1 = *(const float4*)(xrow + k + 4);
        bf16x8 a;
        a[0] = (bf16)f0.x; a[1] = (bf16)f0.y; a[2] = (bf16)f0.z; a[3] = (bf16)f0.w;
        a[4] = (bf16)f1.x; a[5] = (bf16)f1.y; a[6] = (bf16)f1.z; a[7] = (bf16)f1.w;
#pragma unroll
        for (int nt = 0; nt < 8; nt++) {
            int n = nt * 16 + c;
            bf16x8 b1 = *(const bf16x8*)(W1 + n * D + k);
            acc1[nt] = __builtin_amdgcn_mfma_f32_16x16x32_bf16(a, b1, acc1[nt], 0, 0, 0);
            if (two) {
                bf16x8 b2 = *(const bf16x8*)(W2 + n * D + k);
                acc2[nt] = __builtin_amdgcn_mfma_f32_16x16x32_bf16(a, b2, acc2[nt], 0, 0, 0);
            }
        }
    }
#pragma unroll
    for (int r = 0; r < 4; r++) {
        int row = mb + q * 4 + r;
        if (row < M) {
            bf16* p1 = y1 + (long)row * D + c;
#pragma unroll
            for (int nt = 0; nt < 8; nt++)
                p1[nt * 16] = (bf16)fmaxf(acc1[nt][r], 0.f);
            if (two) {
                bf16* p2 = y2 + (long)row * D + c;
#pragma unroll
                for (int nt = 0; nt < 8; nt++)
                    p2[nt * 16] = (bf16)fmaxf(acc2[nt][r], 0.f);
            }
        }
    }
}

__global__ __launch_bounds__(256) void transform_kernel(
    const float* __restrict__ x_drug, const float* __restrict__ x_prot,
    const bf16* __restrict__ Wdd, const bf16* __restrict__ Wdp,
    const bf16* __restrict__ Wpd,
    bf16* __restrict__ y_dd, bf16* __restrict__ y_dp, bf16* __restrict__ y_pd)
{
    int blk = blockIdx.x;
    if (blk < NBLK_D)
        transform_body(x_drug, Wdd, Wdp, y_dd, y_dp, ND, blk, true);
    else
        transform_body(x_prot, Wpd, Wpd, y_pd, y_pd, NP, blk - NBLK_D, false);
}

// ---------------- CSR build ------------------------------------------------
__global__ __launch_bounds__(256) void hist_kernel(
    const int* __restrict__ dd_dst, const int* __restrict__ pd_dst,
    const int* __restrict__ dp_dst, int* __restrict__ C)
{
    int e = blockIdx.x * 256 + threadIdx.x;
    int didx;
    if (e < NE_DD) didx = dd_dst[e];
    else if (e < NE_DD + NE_PD) didx = ND + pd_dst[e - NE_DD];
    else if (e < NE_TOT) didx = 2 * ND + dp_dst[e - NE_DD - NE_PD];
    else return;
    atomicAdd(C + didx, 1);
}

__global__ __launch_bounds__(256) void scan1_kernel(
    const int* __restrict__ C, int* __restrict__ local, int* __restrict__ bsum)
{
    __shared__ int ts[256];
    int tid = threadIdx.x;
    int base = blockIdx.x * 1024 + tid * 4;
    int4 v = *(const int4*)(C + base);
    int s = v.x + v.y + v.z + v.w;
    ts[tid] = s;
    __syncthreads();
#pragma unroll
    for (int off = 1; off < 256; off <<= 1) {
        int add = (tid >= off) ? ts[tid - off] : 0;
        __syncthreads();
        ts[tid] += add;
        __syncthreads();
    }
    int excl = ts[tid] - s;
    if (tid == 255) bsum[blockIdx.x] = ts[255];
    int4 w;
    w.x = excl;
    w.y = excl + v.x;
    w.z = w.y + v.y;
    w.w = w.z + v.z;
    *(int4*)(local + base) = w;
}

__global__ __launch_bounds__(256) void scan2_kernel(int* __restrict__ bsum)
{
    __shared__ int ts[256];
    int tid = threadIdx.x;
    int v = (tid < NB) ? bsum[tid] : 0;
    ts[tid] = v;
    __syncthreads();
#pragma unroll
    for (int off = 1; off < 256; off <<= 1) {
        int add = (tid >= off) ? ts[tid - off] : 0;
        __syncthreads();
        ts[tid] += add;
        __syncthreads();
    }
    if (tid < NB) bsum[tid] = ts[tid] - v;
}

__global__ __launch_bounds__(256) void fill_kernel(
    const int* __restrict__ dd_src, const int* __restrict__ dd_dst,
    const int* __restrict__ pd_src, const int* __restrict__ pd_dst,
    const int* __restrict__ dp_src, const int* __restrict__ dp_dst,
    const int* __restrict__ local, const int* __restrict__ bsum,
    int* __restrict__ cur, int* __restrict__ pool)
{
    int e = blockIdx.x * 256 + threadIdx.x;
    int sidv, didx;
    if (e < NE_DD) { sidv = dd_src[e]; didx = dd_dst[e]; }
    else if (e < NE_DD + NE_PD) { int t = e - NE_DD; sidv = pd_src[t]; didx = ND + pd_dst[t]; }
    else if (e < NE_TOT) { int t = e - NE_DD - NE_PD; sidv = dp_src[t]; didx = 2 * ND + dp_dst[t]; }
    else return;
    int base = local[didx] + bsum[didx >> 10];
    int pos = base + atomicAdd(cur + didx, 1);
    pool[pos] = sidv;
}

// ---------------- gather: 4 edges in flight per wave, 16B/lane -------------
// quad q = lane>>4 owns edge slot q; lane c = lane&15 owns columns c*8..c*8+7.
__global__ __launch_bounds__(256) void gather_kernel(
    const int* __restrict__ local, const int* __restrict__ bsum,
    const int* __restrict__ pool,
    const bf16* __restrict__ y_dd, const bf16* __restrict__ y_pd,
    const bf16* __restrict__ y_dp,
    bf16* __restrict__ agg_d, bf16* __restrict__ agg_p)
{
    int wid = blockIdx.x * 4 + (threadIdx.x >> 6);
    int lane = threadIdx.x & 63;
    int q = lane >> 4;
    int c = lane & 15;

    if (wid < ND) {
        int g = wid;
        int s1 = local[g] + bsum[g >> 10];
        int e1 = local[g + 1] + bsum[(g + 1) >> 10];
        int s2 = local[ND + g] + bsum[(ND + g) >> 10];
        int e2 = local[ND + g + 1] + bsum[(ND + g + 1) >> 10];
        float a[8] = {0.f, 0.f, 0.f, 0.f, 0.f, 0.f, 0.f, 0.f};
        float b[8] = {0.f, 0.f, 0.f, 0.f, 0.f, 0.f, 0.f, 0.f};
        for (int j = s1 + q; j < e1; j += 4) {
            int sid = pool[j];
            bf16x8 v = *(const bf16x8*)(y_dd + (long)sid * D + c * 8);
#pragma unroll
            for (int k = 0; k < 8; k++) a[k] += (float)v[k];
        }
        for (int j = s2 + q; j < e2; j += 4) {
            int sid = pool[j];
            bf16x8 v = *(const bf16x8*)(y_pd + (long)sid * D + c * 8);
#pragma unroll
            for (int k = 0; k < 8; k++) b[k] += (float)v[k];
        }
        float i1 = 0.5f / (float)max(e1 - s1, 1);
        float i2 = 0.5f / (float)max(e2 - s2, 1);
        bf16x8 o;
#pragma unroll
        for (int k = 0; k < 8; k++) {
            float t = a[k] * i1 + b[k] * i2;
            t += __shfl_xor(t, 16, 64);
            t += __shfl_xor(t, 32, 64);
            o[k] = (bf16)t;
        }
        if (q == 0)
            *(bf16x8*)(agg_d + (long)g * D + c * 8) = o;
    } else if (wid < ND + NP) {
        int p = wid - ND;
        int s1 = local[2 * ND + p] + bsum[(2 * ND + p) >> 10];
        int e1 = local[2 * ND + p + 1] + bsum[(2 * ND + p + 1) >> 10];
        float a[8] = {0.f, 0.f, 0.f, 0.f, 0.f, 0.f, 0.f, 0.f};
        for (int j = s1 + q; j < e1; j += 4) {
            int sid = pool[j];
            bf16x8 v = *(const bf16x8*)(y_dp + (long)sid * D + c * 8);
#pragma unroll
            for (int k = 0; k < 8; k++) a[k] += (float)v[k];
        }
        float i1 = 1.0f / (float)max(e1 - s1, 1);
        bf16x8 o;
#pragma unroll
        for (int k = 0; k < 8; k++) {
            float t = a[k] * i1;
            t += __shfl_xor(t, 16, 64);
            t += __shfl_xor(t, 32, 64);
            o[k] = (bf16)t;
        }
        if (q == 0)
            *(bf16x8*)(agg_p + (long)p * D + c * 8) = o;
    }
}

// ---------------- fused node update: GEMM(K=256) + bias+relu+residual+LN ---
__device__ __forceinline__ void node_update_body(
    const float* __restrict__ x, const bf16* __restrict__ agg,
    const bf16* __restrict__ W, const float* __restrict__ b,
    const float* __restrict__ g, const float* __restrict__ be,
    float* __restrict__ out, int M, int blk)
{
    int lane = threadIdx.x & 63;
    int wave = threadIdx.x >> 6;
    int q = lane >> 4, c = lane & 15;
    int mb = blk * 64 + wave * 16;
    int rowA = min(mb + c, M - 1);

    f32x4 acc[8];
#pragma unroll
    for (int i = 0; i < 8; i++) acc[i] = 0;

    const float* xrow = x + (long)rowA * D;
    const bf16* arow  = agg + (long)rowA * D;

#pragma unroll
    for (int kb = 0; kb < 8; kb++) {
        bf16x8 a;
        if (kb < 4) {
            int k = kb * 32 + q * 8;
            float4 f0 = *(const float4*)(xrow + k);
            float4 f1 = *(const float4*)(xrow + k + 4);
            a[0] = (bf16)f0.x; a[1] = (bf16)f0.y; a[2] = (bf16)f0.z; a[3] = (bf16)f0.w;
            a[4] = (bf16)f1.x; a[5] = (bf16)f1.y; a[6] = (bf16)f1.z; a[7] = (bf16)f1.w;
        } else {
            a = *(const bf16x8*)(arow + (kb - 4) * 32 + q * 8);
        }
#pragma unroll
        for (int nt = 0; nt < 8; nt++) {
            int n = nt * 16 + c;
            bf16x8 bw = *(const bf16x8*)(W + n * (2 * D) + kb * 32 + q * 8);
            acc[nt] = __builtin_amdgcn_mfma_f32_16x16x32_bf16(a, bw, acc[nt], 0, 0, 0);
        }
    }

    float bv[8], gv[8], bev[8];
#pragma unroll
    for (int nt = 0; nt < 8; nt++) {
        int col = nt * 16 + c;
        bv[nt] = b[col]; gv[nt] = g[col]; bev[nt] = be[col];
    }
#pragma unroll
    for (int r = 0; r < 4; r++) {
        int row = mb + q * 4 + r;
        int rowc = min(row, M - 1);
        const float* xr = x + (long)rowc * D + c;
        float v[8];
        float sum = 0.f, sq = 0.f;
#pragma unroll
        for (int nt = 0; nt < 8; nt++) {
            float h = fmaxf(acc[nt][r] + bv[nt], 0.f);
            float t = h + xr[nt * 16];
            v[nt] = t; sum += t; sq += t * t;
        }
#pragma unroll
        for (int m = 1; m < 16; m <<= 1) {
            sum += __shfl_xor(sum, m, 64);
            sq  += __shfl_xor(sq,  m, 64);
        }
        float mu   = sum * (1.f / 128.f);
        float var  = sq  * (1.f / 128.f) - mu * mu;
        float rstd = rsqrtf(var + 1e-5f);
        if (row < M) {
            float* op = out + (long)row * D + c;
#pragma unroll
            for (int nt = 0; nt < 8; nt++)
                op[nt * 16] = (v[nt] - mu) * rstd * gv[nt] + bev[nt];
        }
    }
}

__global__ __launch_bounds__(256) void node_update_kernel(
    const float* __restrict__ x_drug, const float* __restrict__ x_prot,
    const bf16* __restrict__ agg_d, const bf16* __restrict__ agg_p,
    const bf16* __restrict__ Wdrug, const float* __restrict__ b_drug,
    const float* __restrict__ g_drug, const float* __restrict__ be_drug,
    const bf16* __restrict__ Wprot, const float* __restrict__ b_prot,
    const float* __restrict__ g_prot, const float* __restrict__ be_prot,
    float* __restrict__ out)
{
    int blk = blockIdx.x;
    if (blk < NBLK_D)
        node_update_body(x_drug, agg_d, Wdrug, b_drug, g_drug, be_drug,
                         out, ND, blk);
    else
        node_update_body(x_prot, agg_p, Wprot, b_prot, g_prot, be_prot,
                         out + (long)ND * D, NP, blk - NBLK_D);
}

extern "C" void kernel_launch(void* const* d_in, const int* in_sizes, int n_in,
                              void* d_out, int out_size, void* d_ws, size_t ws_size,
                              hipStream_t stream)
{
    const float* x_drug  = (const float*)d_in[0];
    const float* x_prot  = (const float*)d_in[1];
    const float* Wagg_dd = (const float*)d_in[2];
    const float* Wagg_dp = (const float*)d_in[3];
    const float* Wagg_pd = (const float*)d_in[4];
    const float* W_drug  = (const float*)d_in[5];
    const float* b_drug  = (const float*)d_in[6];
    const float* W_prot  = (const float*)d_in[7];
    const float* b_prot  = (const float*)d_in[8];
    const float* g_drug  = (const float*)d_in[9];
    const float* be_drug = (const float*)d_in[10];
    const float* g_prot  = (const float*)d_in[11];
    const float* be_prot = (const float*)d_in[12];
    const int* dd_src = (const int*)d_in[13];
    const int* dd_dst = (const int*)d_in[14];
    const int* dp_src = (const int*)d_in[15];
    const int* dp_dst = (const int*)d_in[16];
    const int* pd_src = (const int*)d_in[17];
    const int* pd_dst = (const int*)d_in[18];

    char* ws = (char*)d_ws;
    bf16* Wdd   = (bf16*)(ws + OFF_WDD);
    bf16* Wdp   = (bf16*)(ws + OFF_WDP);
    bf16* Wpd   = (bf16*)(ws + OFF_WPD);
    bf16* Wdrug = (bf16*)(ws + OFF_WDRUG);
    bf16* Wprot = (bf16*)(ws + OFF_WPROT);
    bf16* y_dd  = (bf16*)(ws + OFF_YDD);
    bf16* y_dp  = (bf16*)(ws + OFF_YDP);
    bf16* y_pd  = (bf16*)(ws + OFF_YPD);
    bf16* agg_d = (bf16*)(ws + OFF_AGGD);
    bf16* agg_p = (bf16*)(ws + OFF_AGGP);
    int* C      = (int*)(ws + OFF_C);
    int* cur    = (int*)(ws + OFF_CUR2);
    int* local  = (int*)(ws + OFF_LOCAL);
    int* bsum   = (int*)(ws + OFF_BSUM);
    int* pool   = (int*)(ws + OFF_POOL);
    float* out  = (float*)d_out;

    // 1) weights->bf16 + zero histogram/cursors (2 MB)
    prep_kernel<<<dim3(490, 6), 256, 0, stream>>>(
        Wagg_dd, Wagg_dp, Wagg_pd, W_drug, W_prot,
        Wdd, Wdp, Wpd, Wdrug, Wprot, (float4*)C);

    // 2) per-node transforms (drug: dd+dp, prot: pd)
    transform_kernel<<<NBLK_D + NBLK_P, 256, 0, stream>>>(
        x_drug, x_prot, Wdd, Wdp, Wpd, y_dd, y_dp, y_pd);

    // 3) CSR build: histogram -> 2-level scan -> cursor fill
    hist_kernel<<<(NE_TOT + 255) / 256, 256, 0, stream>>>(dd_dst, pd_dst, dp_dst, C);
    scan1_kernel<<<NB, 256, 0, stream>>>(C, local, bsum);
    scan2_kernel<<<1, 256, 0, stream>>>(bsum);
    fill_kernel<<<(NE_TOT + 255) / 256, 256, 0, stream>>>(
        dd_src, dd_dst, pd_src, pd_dst, dp_src, dp_dst, local, bsum, cur, pool);

    // 4) gather + per-relation mean (4 edges in flight per wave)
    gather_kernel<<<(ND + NP + 3) / 4, 256, 0, stream>>>(
        local, bsum, pool, y_dd, y_pd, y_dp, agg_d, agg_p);

    // 5) fused node updates (drug rows then prot rows of out)
    node_update_kernel<<<NBLK_D + NBLK_P, 256, 0, stream>>>(
        x_drug, x_prot, agg_d, agg_p,
        Wdrug, b_drug, g_drug, be_drug,
        Wprot, b_prot, g_prot, be_prot, out);
}

// Round 4
// 482.666 us; speedup vs baseline: 7.8465x; 1.2260x over previous
//
#include <hip/hip_runtime.h>

#define D 128
#define ND 100000
#define NP 50000
#define NE_DD 800000
#define NE_DP 600000
#define NE_PD 600000
#define NE_TOT 2000000

#define NTOT 250000      /* concatenated dst space: [dd:100k][pd:100k][dp:50k] */
#define NBC 490          /* coarse buckets, 512 nodes each (490*512 = 250880) */
#define NC 250880
#define CHUNKA 8192      /* edges per binning block */
#define NBLKA 245        /* ceil(2M/8192) */
#define SEGCAP 8192      /* max edges per coarse bucket (expected max ~6.6k) */

#define NBLK_D 1563      /* (ND+63)/64 */
#define NBLK_P 782       /* (NP+63)/64 */

typedef __bf16 bf16;
typedef __attribute__((ext_vector_type(8))) __bf16 bf16x8;
typedef __attribute__((ext_vector_type(4))) float f32x4;

// ---------------- workspace layout (byte offsets, 16B-aligned) -------------
#define OFF_WDD   0UL
#define OFF_WDP   32768UL
#define OFF_WPD   65536UL
#define OFF_WDRUG 98304UL
#define OFF_WPROT 163840UL
#define OFF_YDD   229376UL                      /* 100k x 128 bf16 */
#define OFF_YDP   (OFF_YDD + 25600000UL)        /* 100k x 128 bf16 */
#define OFF_YPD   (OFF_YDP + 25600000UL)        /* 50k x 128 bf16 */
#define OFF_AGGD  (OFF_YPD + 12800000UL)        /* 100k x 128 bf16 */
#define OFF_AGGP  (OFF_AGGD + 25600000UL)       /* 50k x 128 bf16 */
#define OFF_BCNT  (OFF_AGGP + 12800000UL)       /* NBC ints (zeroed in prep) */
#define OFF_GCUR  (OFF_BCNT + 2048UL)           /* NBC ints */
#define OFF_CBASE (OFF_GCUR + 2048UL)           /* NBC+1 ints */
#define OFF_RP    (OFF_CBASE + 2048UL)          /* NC ints (row ptrs) */
#define OFF_PAIRS (OFF_RP + 1003520UL)          /* 2M int2 (bucket-grouped) */
#define OFF_POOL  (OFF_PAIRS + 16000000UL)      /* 2M ints (node-grouped src) */

// ---------------- prep: weights->bf16  +  zero bcnt ------------------------
__global__ __launch_bounds__(256) void prep_kernel(
    const float* __restrict__ w0, const float* __restrict__ w1,
    const float* __restrict__ w2, const float* __restrict__ w3,
    const float* __restrict__ w4,
    bf16* __restrict__ o0, bf16* __restrict__ o1, bf16* __restrict__ o2,
    bf16* __restrict__ o3, bf16* __restrict__ o4,
    int* __restrict__ bcnt)
{
    int m = blockIdx.y;
    int i = blockIdx.x * 256 + threadIdx.x;
    if (m == 5) {
        if (i < NBC) bcnt[i] = 0;
        return;
    }
    const float* src; bf16* dst; int n;
    switch (m) {
        case 0: src = w0; dst = o0; n = D * D; break;
        case 1: src = w1; dst = o1; n = D * D; break;
        case 2: src = w2; dst = o2; n = D * D; break;
        case 3: src = w3; dst = o3; n = D * 2 * D; break;
        default: src = w4; dst = o4; n = D * 2 * D; break;
    }
    if (i < n) dst[i] = (bf16)src[i];
}

// ---------------- per-node transforms: y = relu(x @ W^T), both types -------
__device__ __forceinline__ void transform_body(
    const float* __restrict__ x, const bf16* __restrict__ W1,
    const bf16* __restrict__ W2, bf16* __restrict__ y1, bf16* __restrict__ y2,
    int M, int blk, bool two)
{
    int lane = threadIdx.x & 63;
    int wave = threadIdx.x >> 6;
    int q = lane >> 4, c = lane & 15;
    int mb = blk * 64 + wave * 16;
    int rowA = min(mb + c, M - 1);

    f32x4 acc1[8], acc2[8];
#pragma unroll
    for (int i = 0; i < 8; i++) { acc1[i] = 0; acc2[i] = 0; }

    const float* xrow = x + (long)rowA * D;
#pragma unroll
    for (int kb = 0; kb < 4; kb++) {
        int k = kb * 32 + q * 8;
        float4 f0 = *(const float4*)(xrow + k);
        float4 f1 = *(const float4*)(xrow + k + 4);
        bf16x8 a;
        a[0] = (bf16)f0.x; a[1] = (bf16)f0.y; a[2] = (bf16)f0.z; a[3] = (bf16)f0.w;
        a[4] = (bf16)f1.x; a[5] = (bf16)f1.y; a[6] = (bf16)f1.z; a[7] = (bf16)f1.w;
#pragma unroll
        for (int nt = 0; nt < 8; nt++) {
            int n = nt * 16 + c;
            bf16x8 b1 = *(const bf16x8*)(W1 + n * D + k);
            acc1[nt] = __builtin_amdgcn_mfma_f32_16x16x32_bf16(a, b1, acc1[nt], 0, 0, 0);
            if (two) {
                bf16x8 b2 = *(const bf16x8*)(W2 + n * D + k);
                acc2[nt] = __builtin_amdgcn_mfma_f32_16x16x32_bf16(a, b2, acc2[nt], 0, 0, 0);
            }
        }
    }
#pragma unroll
    for (int r = 0; r < 4; r++) {
        int row = mb + q * 4 + r;
        if (row < M) {
            bf16* p1 = y1 + (long)row * D + c;
#pragma unroll
            for (int nt = 0; nt < 8; nt++)
                p1[nt * 16] = (bf16)fmaxf(acc1[nt][r], 0.f);
            if (two) {
                bf16* p2 = y2 + (long)row * D + c;
#pragma unroll
                for (int nt = 0; nt < 8; nt++)
                    p2[nt * 16] = (bf16)fmaxf(acc2[nt][r], 0.f);
            }
        }
    }
}

__global__ __launch_bounds__(256) void transform_kernel(
    const float* __restrict__ x_drug, const float* __restrict__ x_prot,
    const bf16* __restrict__ Wdd, const bf16* __restrict__ Wdp,
    const bf16* __restrict__ Wpd,
    bf16* __restrict__ y_dd, bf16* __restrict__ y_dp, bf16* __restrict__ y_pd)
{
    int blk = blockIdx.x;
    if (blk < NBLK_D)
        transform_body(x_drug, Wdd, Wdp, y_dd, y_dp, ND, blk, true);
    else
        transform_body(x_prot, Wpd, Wpd, y_pd, y_pd, NP, blk - NBLK_D, false);
}

// ---------------- coarse histogram (LDS-staged) ----------------------------
__global__ __launch_bounds__(256) void hist_kernel(
    const int* __restrict__ dd_dst, const int* __restrict__ pd_dst,
    const int* __restrict__ dp_dst, int* __restrict__ bcnt)
{
    __shared__ int h[NBC];
    for (int i = threadIdx.x; i < NBC; i += 256) h[i] = 0;
    __syncthreads();
    int base = blockIdx.x * CHUNKA;
    for (int it = 0; it < 32; it++) {
        int e = base + it * 256 + threadIdx.x;
        if (e < NE_TOT) {
            int didx;
            if (e < NE_DD) didx = dd_dst[e];
            else if (e < NE_DD + NE_PD) didx = ND + pd_dst[e - NE_DD];
            else didx = 2 * ND + dp_dst[e - NE_DD - NE_PD];
            atomicAdd(&h[didx >> 9], 1);
        }
    }
    __syncthreads();
    for (int i = threadIdx.x; i < NBC; i += 256)
        if (h[i]) atomicAdd(&bcnt[i], h[i]);
}

// ---------------- exclusive scan over 490 bucket counts (1 block) ----------
__global__ __launch_bounds__(256) void scan_kernel(
    const int* __restrict__ bcnt, int* __restrict__ cbase, int* __restrict__ gcur)
{
    __shared__ int ps[256];
    int t = threadIdx.x;
    int i0 = 2 * t, i1 = 2 * t + 1;
    int c0 = (i0 < NBC) ? bcnt[i0] : 0;
    int c1 = (i1 < NBC) ? bcnt[i1] : 0;
    ps[t] = c0 + c1;
    __syncthreads();
#pragma unroll
    for (int off = 1; off < 256; off <<= 1) {
        int add = (t >= off) ? ps[t - off] : 0;
        __syncthreads();
        ps[t] += add;
        __syncthreads();
    }
    int excl = ps[t] - (c0 + c1);
    if (i0 <= NBC) cbase[i0] = excl;            /* i0==NBC writes the sentinel */
    if (i0 < NBC) gcur[i0] = excl;
    if (i1 < NBC) { cbase[i1] = excl + c0; gcur[i1] = excl + c0; }
}

// ---------------- pass A: coarse binning with block-dense runs -------------
__global__ __launch_bounds__(256) void binA_kernel(
    const int* __restrict__ dd_src, const int* __restrict__ dd_dst,
    const int* __restrict__ pd_src, const int* __restrict__ pd_dst,
    const int* __restrict__ dp_src, const int* __restrict__ dp_dst,
    int* __restrict__ gcur, int2* __restrict__ pairs)
{
    __shared__ int h[NBC];
    __shared__ int gb[NBC];
    __shared__ int2 pr[CHUNKA];
    __shared__ unsigned short rk[CHUNKA];
    for (int i = threadIdx.x; i < NBC; i += 256) h[i] = 0;
    __syncthreads();
    int base = blockIdx.x * CHUNKA;
    for (int it = 0; it < 32; it++) {
        int idx = it * 256 + threadIdx.x;
        int e = base + idx;
        int didx = -1, sv = 0;
        if (e < NE_TOT) {
            if (e < NE_DD) { didx = dd_dst[e]; sv = dd_src[e]; }
            else if (e < NE_DD + NE_PD) { int u = e - NE_DD; didx = ND + pd_dst[u]; sv = pd_src[u]; }
            else { int u = e - NE_DD - NE_PD; didx = 2 * ND + dp_dst[u]; sv = dp_src[u]; }
            rk[idx] = (unsigned short)atomicAdd(&h[didx >> 9], 1);
        }
        pr[idx] = make_int2(didx, sv);
    }
    __syncthreads();
    for (int b = threadIdx.x; b < NBC; b += 256) {
        int c = h[b];
        gb[b] = c ? atomicAdd(&gcur[b], c) : 0;
    }
    __syncthreads();
    for (int it = 0; it < 32; it++) {
        int idx = it * 256 + threadIdx.x;
        int2 p = pr[idx];
        if (p.x >= 0) pairs[gb[p.x >> 9] + rk[idx]] = p;
    }
}

// ---------------- pass B: per-bucket LDS counting sort -> pool + rp --------
__global__ __launch_bounds__(256) void sortB_kernel(
    const int* __restrict__ cbase, const int2* __restrict__ pairs,
    int* __restrict__ pool, int* __restrict__ rp)
{
    __shared__ int h[512];
    __shared__ int excl[512];
    __shared__ int ps[256];
    __shared__ int srcl[SEGCAP];
    __shared__ unsigned short ll[SEGCAP];
    __shared__ unsigned short rk[SEGCAP];
    __shared__ int outl[SEGCAP];

    int b = blockIdx.x;
    int s0 = cbase[b], s1 = cbase[b + 1];
    int n = s1 - s0;
    if (n > SEGCAP) n = SEGCAP;   /* safety clamp; expected max ~6.6k */
    int t = threadIdx.x;
    h[t] = 0; h[t + 256] = 0;
    __syncthreads();

    for (int i = t; i < n; i += 256) {
        int2 p = pairs[s0 + i];
        int l = p.x & 511;
        srcl[i] = p.y;
        ll[i] = (unsigned short)l;
        rk[i] = (unsigned short)atomicAdd(&h[l], 1);
    }
    __syncthreads();

    // exclusive scan over h[0..511] (2 elems per thread)
    int c0 = h[2 * t], c1 = h[2 * t + 1];
    ps[t] = c0 + c1;
    __syncthreads();
#pragma unroll
    for (int off = 1; off < 256; off <<= 1) {
        int add = (t >= off) ? ps[t - off] : 0;
        __syncthreads();
        ps[t] += add;
        __syncthreads();
    }
    int pe = ps[t] - (c0 + c1);
    excl[2 * t] = pe;
    excl[2 * t + 1] = pe + c0;
    __syncthreads();

    // row pointers for this bucket's 512 node slots
    int nb = b * 512;
    rp[nb + 2 * t] = s0 + excl[2 * t];
    rp[nb + 2 * t + 1] = s0 + excl[2 * t + 1];

    // LDS scatter, then coalesced copy out
    for (int i = t; i < n; i += 256)
        outl[excl[ll[i]] + rk[i]] = srcl[i];
    __syncthreads();
    for (int i = t; i < n; i += 256)
        pool[s0 + i] = outl[i];
}

// ---------------- gather: 4 edges in flight per wave, 16B/lane -------------
__global__ __launch_bounds__(256) void gather_kernel(
    const int* __restrict__ rp, const int* __restrict__ pool,
    const bf16* __restrict__ y_dd, const bf16* __restrict__ y_pd,
    const bf16* __restrict__ y_dp,
    bf16* __restrict__ agg_d, bf16* __restrict__ agg_p)
{
    int wid = blockIdx.x * 4 + (threadIdx.x >> 6);
    int lane = threadIdx.x & 63;
    int q = lane >> 4;
    int c = lane & 15;

    if (wid < ND) {
        int g = wid;
        int s1 = rp[g], e1 = rp[g + 1];
        int s2 = rp[ND + g], e2 = rp[ND + g + 1];
        float a[8] = {0.f, 0.f, 0.f, 0.f, 0.f, 0.f, 0.f, 0.f};
        float b[8] = {0.f, 0.f, 0.f, 0.f, 0.f, 0.f, 0.f, 0.f};
        for (int j = s1 + q; j < e1; j += 4) {
            int sid = pool[j];
            bf16x8 v = *(const bf16x8*)(y_dd + (long)sid * D + c * 8);
#pragma unroll
            for (int k = 0; k < 8; k++) a[k] += (float)v[k];
        }
        for (int j = s2 + q; j < e2; j += 4) {
            int sid = pool[j];
            bf16x8 v = *(const bf16x8*)(y_pd + (long)sid * D + c * 8);
#pragma unroll
            for (int k = 0; k < 8; k++) b[k] += (float)v[k];
        }
        float i1 = 0.5f / (float)max(e1 - s1, 1);
        float i2 = 0.5f / (float)max(e2 - s2, 1);
        bf16x8 o;
#pragma unroll
        for (int k = 0; k < 8; k++) {
            float tt = a[k] * i1 + b[k] * i2;
            tt += __shfl_xor(tt, 16, 64);
            tt += __shfl_xor(tt, 32, 64);
            o[k] = (bf16)tt;
        }
        if (q == 0)
            *(bf16x8*)(agg_d + (long)g * D + c * 8) = o;
    } else if (wid < ND + NP) {
        int p = wid - ND;
        int s1 = rp[2 * ND + p], e1 = rp[2 * ND + p + 1];
        float a[8] = {0.f, 0.f, 0.f, 0.f, 0.f, 0.f, 0.f, 0.f};
        for (int j = s1 + q; j < e1; j += 4) {
            int sid = pool[j];
            bf16x8 v = *(const bf16x8*)(y_dp + (long)sid * D + c * 8);
#pragma unroll
            for (int k = 0; k < 8; k++) a[k] += (float)v[k];
        }
        float i1 = 1.0f / (float)max(e1 - s1, 1);
        bf16x8 o;
#pragma unroll
        for (int k = 0; k < 8; k++) {
            float tt = a[k] * i1;
            tt += __shfl_xor(tt, 16, 64);
            tt += __shfl_xor(tt, 32, 64);
            o[k] = (bf16)tt;
        }
        if (q == 0)
            *(bf16x8*)(agg_p + (long)p * D + c * 8) = o;
    }
}

// ---------------- fused node update: GEMM(K=256) + bias+relu+residual+LN ---
__device__ __forceinline__ void node_update_body(
    const float* __restrict__ x, const bf16* __restrict__ agg,
    const bf16* __restrict__ W, const float* __restrict__ b,
    const float* __restrict__ g, const float* __restrict__ be,
    float* __restrict__ out, int M, int blk)
{
    int lane = threadIdx.x & 63;
    int wave = threadIdx.x >> 6;
    int q = lane >> 4, c = lane & 15;
    int mb = blk * 64 + wave * 16;
    int rowA = min(mb + c, M - 1);

    f32x4 acc[8];
#pragma unroll
    for (int i = 0; i < 8; i++) acc[i] = 0;

    const float* xrow = x + (long)rowA * D;
    const bf16* arow  = agg + (long)rowA * D;

#pragma unroll
    for (int kb = 0; kb < 8; kb++) {
        bf16x8 a;
        if (kb < 4) {
            int k = kb * 32 + q * 8;
            float4 f0 = *(const float4*)(xrow + k);
            float4 f1 = *(const float4*)(xrow + k + 4);
            a[0] = (bf16)f0.x; a[1] = (bf16)f0.y; a[2] = (bf16)f0.z; a[3] = (bf16)f0.w;
            a[4] = (bf16)f1.x; a[5] = (bf16)f1.y; a[6] = (bf16)f1.z; a[7] = (bf16)f1.w;
        } else {
            a = *(const bf16x8*)(arow + (kb - 4) * 32 + q * 8);
        }
#pragma unroll
        for (int nt = 0; nt < 8; nt++) {
            int n = nt * 16 + c;
            bf16x8 bw = *(const bf16x8*)(W + n * (2 * D) + kb * 32 + q * 8);
            acc[nt] = __builtin_amdgcn_mfma_f32_16x16x32_bf16(a, bw, acc[nt], 0, 0, 0);
        }
    }

    float bv[8], gv[8], bev[8];
#pragma unroll
    for (int nt = 0; nt < 8; nt++) {
        int col = nt * 16 + c;
        bv[nt] = b[col]; gv[nt] = g[col]; bev[nt] = be[col];
    }
#pragma unroll
    for (int r = 0; r < 4; r++) {
        int row = mb + q * 4 + r;
        int rowc = min(row, M - 1);
        const float* xr = x + (long)rowc * D + c;
        float v[8];
        float sum = 0.f, sq = 0.f;
#pragma unroll
        for (int nt = 0; nt < 8; nt++) {
            float h = fmaxf(acc[nt][r] + bv[nt], 0.f);
            float t = h + xr[nt * 16];
            v[nt] = t; sum += t; sq += t * t;
        }
#pragma unroll
        for (int m = 1; m < 16; m <<= 1) {
            sum += __shfl_xor(sum, m, 64);
            sq  += __shfl_xor(sq,  m, 64);
        }
        float mu   = sum * (1.f / 128.f);
        float var  = sq  * (1.f / 128.f) - mu * mu;
        float rstd = rsqrtf(var + 1e-5f);
        if (row < M) {
            float* op = out + (long)row * D + c;
#pragma unroll
            for (int nt = 0; nt < 8; nt++)
                op[nt * 16] = (v[nt] - mu) * rstd * gv[nt] + bev[nt];
        }
    }
}

__global__ __launch_bounds__(256) void node_update_kernel(
    const float* __restrict__ x_drug, const float* __restrict__ x_prot,
    const bf16* __restrict__ agg_d, const bf16* __restrict__ agg_p,
    const bf16* __restrict__ Wdrug, const float* __restrict__ b_drug,
    const float* __restrict__ g_drug, const float* __restrict__ be_drug,
    const bf16* __restrict__ Wprot, const float* __restrict__ b_prot,
    const float* __restrict__ g_prot, const float* __restrict__ be_prot,
    float* __restrict__ out)
{
    int blk = blockIdx.x;
    if (blk < NBLK_D)
        node_update_body(x_drug, agg_d, Wdrug, b_drug, g_drug, be_drug,
                         out, ND, blk);
    else
        node_update_body(x_prot, agg_p, Wprot, b_prot, g_prot, be_prot,
                         out + (long)ND * D, NP, blk - NBLK_D);
}

extern "C" void kernel_launch(void* const* d_in, const int* in_sizes, int n_in,
                              void* d_out, int out_size, void* d_ws, size_t ws_size,
                              hipStream_t stream)
{
    const float* x_drug  = (const float*)d_in[0];
    const float* x_prot  = (const float*)d_in[1];
    const float* Wagg_dd = (const float*)d_in[2];
    const float* Wagg_dp = (const float*)d_in[3];
    const float* Wagg_pd = (const float*)d_in[4];
    const float* W_drug  = (const float*)d_in[5];
    const float* b_drug  = (const float*)d_in[6];
    const float* W_prot  = (const float*)d_in[7];
    const float* b_prot  = (const float*)d_in[8];
    const float* g_drug  = (const float*)d_in[9];
    const float* be_drug = (const float*)d_in[10];
    const float* g_prot  = (const float*)d_in[11];
    const float* be_prot = (const float*)d_in[12];
    const int* dd_src = (const int*)d_in[13];
    const int* dd_dst = (const int*)d_in[14];
    const int* dp_src = (const int*)d_in[15];
    const int* dp_dst = (const int*)d_in[16];
    const int* pd_src = (const int*)d_in[17];
    const int* pd_dst = (const int*)d_in[18];

    char* ws = (char*)d_ws;
    bf16* Wdd   = (bf16*)(ws + OFF_WDD);
    bf16* Wdp   = (bf16*)(ws + OFF_WDP);
    bf16* Wpd   = (bf16*)(ws + OFF_WPD);
    bf16* Wdrug = (bf16*)(ws + OFF_WDRUG);
    bf16* Wprot = (bf16*)(ws + OFF_WPROT);
    bf16* y_dd  = (bf16*)(ws + OFF_YDD);
    bf16* y_dp  = (bf16*)(ws + OFF_YDP);
    bf16* y_pd  = (bf16*)(ws + OFF_YPD);
    bf16* agg_d = (bf16*)(ws + OFF_AGGD);
    bf16* agg_p = (bf16*)(ws + OFF_AGGP);
    int* bcnt   = (int*)(ws + OFF_BCNT);
    int* gcur   = (int*)(ws + OFF_GCUR);
    int* cbase  = (int*)(ws + OFF_CBASE);
    int* rp     = (int*)(ws + OFF_RP);
    int2* pairs = (int2*)(ws + OFF_PAIRS);
    int* pool   = (int*)(ws + OFF_POOL);
    float* out  = (float*)d_out;

    // 1) weights->bf16 + zero coarse histogram (~2KB)
    prep_kernel<<<dim3(128, 6), 256, 0, stream>>>(
        Wagg_dd, Wagg_dp, Wagg_pd, W_drug, W_prot,
        Wdd, Wdp, Wpd, Wdrug, Wprot, bcnt);

    // 2) per-node transforms (drug: dd+dp, prot: pd)
    transform_kernel<<<NBLK_D + NBLK_P, 256, 0, stream>>>(
        x_drug, x_prot, Wdd, Wdp, Wpd, y_dd, y_dp, y_pd);

    // 3) two-level counting sort of edges by destination
    hist_kernel<<<NBLKA, 256, 0, stream>>>(dd_dst, pd_dst, dp_dst, bcnt);
    scan_kernel<<<1, 256, 0, stream>>>(bcnt, cbase, gcur);
    binA_kernel<<<NBLKA, 256, 0, stream>>>(
        dd_src, dd_dst, pd_src, pd_dst, dp_src, dp_dst, gcur, pairs);
    sortB_kernel<<<NBC, 256, 0, stream>>>(cbase, pairs, pool, rp);

    // 4) gather + per-relation mean (4 edges in flight per wave)
    gather_kernel<<<(ND + NP + 3) / 4, 256, 0, stream>>>(
        rp, pool, y_dd, y_pd, y_dp, agg_d, agg_p);

    // 5) fused node updates (drug rows then prot rows of out)
    node_update_kernel<<<NBLK_D + NBLK_P, 256, 0, stream>>>(
        x_drug, x_prot, agg_d, agg_p,
        Wdrug, b_drug, g_drug, be_drug,
        Wprot, b_prot, g_prot, be_prot, out);
}